// Round 1
// baseline (141.402 us; speedup 1.0000x reference)
//
#include <hip/hip_runtime.h>

// B=4, T=4096, C=512, H=64.  k,q,v = x@W+b; S = k qT/sqrt(C); softmax over q; out = P v.
// R5: attn rewritten barrier-free. No js split (full 4096-j loop per block, 16 steps of
// 256 j, 8 waves jc8). No LDS staging: Q/V fragments load straight from L2-resident
// per-batch slices (1 MB each) into regs; Q frags software-pipelined one step ahead
// (named A/B arrays, static indices). XCD-bijective block swizzle keeps <=1 MB Q/V
// working set per XCD L2. Softmax denominator closes in-block -> direct out write,
// fin kernel and Op/Lp partials deleted (4 -> 3 dispatches, -16 MB HBM).
// proj = single-shot 64KB stage (unchanged). log2(e)/sqrt(C) folded into Wk/bk.

#define DM 512
#define HD 64
#define TSEQ 4096
#define KSCALE (1.4426950408889634f * 0.04419417382415922f) /* log2(e)/sqrt(512) */

typedef __attribute__((ext_vector_type(8))) __bf16 bf16x8;
typedef __attribute__((ext_vector_type(4))) __bf16 bf16x4;
typedef __attribute__((ext_vector_type(2))) __bf16 bf16x2;
typedef __attribute__((ext_vector_type(4))) float f32x4;
typedef __attribute__((ext_vector_type(16))) float f32x16;
typedef __attribute__((ext_vector_type(4))) unsigned int uint4v;

__device__ __forceinline__ float fast_exp2(float x) {
#if __has_builtin(__builtin_amdgcn_exp2f)
    return __builtin_amdgcn_exp2f(x);
#else
    return exp2f(x);
#endif
}

__device__ __forceinline__ bf16x8 ld_bf16x8(const unsigned short* p) {
    return __builtin_bit_cast(bf16x8, *(const uint4v*)p);
}
__device__ __forceinline__ f32x4 mfma16(bf16x8 a, bf16x8 b, f32x4 c) {
    return __builtin_amdgcn_mfma_f32_16x16x32_bf16(a, b, c, 0, 0, 0);
}
__device__ __forceinline__ f32x16 mfma32(bf16x8 a, bf16x8 b, f32x16 c) {
    return __builtin_amdgcn_mfma_f32_32x32x16_bf16(a, b, c, 0, 0, 0);
}

// async global->LDS, 16 B per lane. LDS dst = wave-uniform base + lane*16.
typedef const __attribute__((address_space(1))) unsigned int* gas_t;
typedef __attribute__((address_space(3))) unsigned int* las_t;
__device__ __forceinline__ void async_cp16(const void* g, void* l) {
    __builtin_amdgcn_global_load_lds((gas_t)(unsigned long long)g,
                                     (las_t)(unsigned int)(unsigned long long)l,
                                     16, 0, 0);
}

// ---------------------------------------------------------------- prep: W -> W^T bf16
__global__ __launch_bounds__(256) void prep_wt(const float* __restrict__ Wk,
                                               const float* __restrict__ Wq,
                                               const float* __restrict__ Wv,
                                               unsigned short* __restrict__ WT) {
    int e = blockIdx.x * 256 + threadIdx.x;   // grid 384 = exactly 3*512*64
    int m = e >> 15;
    int idx = e & 32767;
    int h = idx >> 9;
    int cc = idx & 511;
    const float* W = (m == 0) ? Wk : ((m == 1) ? Wq : Wv);
    float v = W[cc * HD + h];
    if (m == 0) v *= KSCALE;
    ((__bf16*)WT)[m * 32768 + h * DM + cc] = (__bf16)v;
}

// ---------------------------------------------------------------- projection
// grid 512 (32 rows each), block 512 = 8 waves: rg = wv>>2 (16 rows), ng = wv&3 (16 cols).
// Whole 32x512 fp32 x-tile (64 KB) staged in ONE shot (8 cps/lane, one vmcnt+barrier).
__global__ __launch_bounds__(512, 4) void proj(const float* __restrict__ x,
                                               const unsigned short* __restrict__ WT,
                                               const float* __restrict__ bk,
                                               const float* __restrict__ bq,
                                               const float* __restrict__ bv,
                                               unsigned short* __restrict__ Kw,
                                               unsigned short* __restrict__ Qw,
                                               unsigned short* __restrict__ VTw) {
    __shared__ alignas(16) float xs[16384];   // 64 KB
    const int tid = threadIdx.x;
    const int wv = tid >> 6, lane = tid & 63;
    const int c = lane & 15, quad = lane >> 4;
    const int ng = wv & 3, rg = wv >> 2;
    const int bx = blockIdx.x;
    const int n0 = ng * 16;

    // stage: 8 rounds, chunk id = r*512+tid; row = id>>7, pos = id&127;
    // slot pos holds global chunk (pos&~7)|((pos^row)&7)  (low-3 xor swizzle)
#pragma unroll
    for (int r = 0; r < 8; ++r) {
        int cid = r * 512 + tid;
        int row = cid >> 7, pos = cid & 127;
        int g = (pos & ~7) | ((pos ^ row) & 7);
        async_cp16((const char*)x + (size_t)(bx * 32 + row) * 2048 + g * 16,
                   (char*)xs + r * 8192 + wv * 1024);
    }
    __builtin_amdgcn_s_waitcnt(0x0f70);   // vmcnt(0)
    __syncthreads();

    const int arow = rg * 16 + c;
    const unsigned short* wtb = WT + (n0 + c) * DM + quad * 8;
    f32x4 acc[3];
#pragma unroll
    for (int m = 0; m < 3; ++m) acc[m] = (f32x4){0.f, 0.f, 0.f, 0.f};

#pragma unroll
    for (int ks = 0; ks < 16; ++ks) {
        int p0 = ks * 8 + quad * 2;
        int sp0 = (p0 & ~7) | ((p0 ^ arow) & 7);
        int sp1 = ((p0 + 1) & ~7) | (((p0 + 1) ^ arow) & 7);
        f32x4 xa = *(const f32x4*)((const char*)xs + arow * 2048 + sp0 * 16);
        f32x4 xb = *(const f32x4*)((const char*)xs + arow * 2048 + sp1 * 16);
        bf16x8 af;
        af[0] = (__bf16)xa[0]; af[1] = (__bf16)xa[1]; af[2] = (__bf16)xa[2]; af[3] = (__bf16)xa[3];
        af[4] = (__bf16)xb[0]; af[5] = (__bf16)xb[1]; af[6] = (__bf16)xb[2]; af[7] = (__bf16)xb[3];
#pragma unroll
        for (int m = 0; m < 3; ++m) {
            bf16x8 bf = ld_bf16x8(wtb + m * 32768 + ks * 32);
            acc[m] = mfma16(af, bf, acc[m]);
        }
    }

    const int row0 = bx * 32 + rg * 16 + quad * 4;
#pragma unroll
    for (int m = 0; m < 3; ++m) {
        const float* bp = (m == 0) ? bk : ((m == 1) ? bq : bv);
        float bias = bp[n0 + c];
        if (m == 0) bias *= KSCALE;
        if (m < 2) {
            __bf16* dst = (__bf16*)((m == 0) ? Kw : Qw);
#pragma unroll
            for (int r = 0; r < 4; ++r)
                dst[(row0 + r) * HD + n0 + c] = (__bf16)(acc[m][r] + bias);
        } else {
            bf16x4 pk;
#pragma unroll
            for (int r = 0; r < 4; ++r) pk[r] = (__bf16)(acc[m][r] + bias);
            int b = bx >> 7;
            int rowb = (bx & 127) * 32 + rg * 16 + quad * 4;
            *(bf16x4*)(VTw + ((size_t)(b * 64 + n0 + c)) * TSEQ + rowb) = pk;
        }
    }
}

// ---------------------------------------------------------------- fused attention
// grid 256 (XCD-swizzled): logical lb = (bx&7)*32 + (bx>>3); batch = lb>>6, tile = lb&63
// (64 i rows). block 512 = 8 waves, jc = wv (32 j of each 256-j step), 16 steps = full
// 4096 j. No LDS in main loop: K frags resident, Q frags double-buffered in regs
// (loaded for step jt+1 during step jt), V frags loaded per step (covered by QK+exp2).
// Epilogue: jc8 partial-O + partial-L combine in LDS, divide, direct out write.
__global__ __launch_bounds__(512, 2) void attn(const unsigned short* __restrict__ Kw,
                                               const unsigned short* __restrict__ Qw,
                                               const unsigned short* __restrict__ VTw,
                                               float* __restrict__ out) {
    __shared__ float OCp[8 * 32 * 34];   // 34816 B, one (ht,it) phase at a time
    __shared__ float ldsl[512];          // [jc8][i64] partial L
    __shared__ float Lrec[64];           // 1/L per row

    const int tid = threadIdx.x;
    const int wv = tid >> 6, lane = tid & 63;
    const int l5 = lane >> 5, l31 = lane & 31;
    const int jc = wv;
    const int bx = blockIdx.x;
    const int lb = (bx & 7) * 32 + (bx >> 3);     // XCD-contiguous logical id
    const int batch = lb >> 6, tile = lb & 63;
    const int ibase = batch * TSEQ + tile * 64;

    // K fragments (B-operand of S', n = i), resident in regs. 64 i rows per block.
    bf16x8 kf0[4], kf1[4];
    {
        const unsigned short* kp0 = Kw + (size_t)(ibase + l31) * HD + l5 * 8;
        const unsigned short* kp1 = Kw + (size_t)(ibase + 32 + l31) * HD + l5 * 8;
#pragma unroll
        for (int ks = 0; ks < 4; ++ks) {
            kf0[ks] = ld_bf16x8(kp0 + ks * 16);
            kf1[ks] = ld_bf16x8(kp1 + ks * 16);
        }
    }

    // per-lane global fragment bases (natural layout, L2-resident slices)
    const unsigned short* qp = Qw + (size_t)(batch * TSEQ + jc * 32 + l31) * HD + l5 * 8;
    const unsigned short* vp = VTw + (size_t)(batch * 64 + l31) * TSEQ + jc * 32 + l5 * 8;

    f32x16 o00, o01, o10, o11;   // o[ht][it]
#pragma unroll
    for (int r = 0; r < 16; ++r) { o00[r] = 0.f; o01[r] = 0.f; o10[r] = 0.f; o11[r] = 0.f; }
    float lac0 = 0.f, lac1 = 0.f;

    bf16x8 qA[4], qB[4];
#pragma unroll
    for (int ks = 0; ks < 4; ++ks) qA[ks] = ld_bf16x8(qp + ks * 16);

    auto STEP = [&](const bf16x8 (&qc)[4], bf16x8 (&qn)[4], int jt) {
        // V frags for this step: issued first, consumed after QK+exp2 (latency cover)
        const unsigned short* vb = vp + jt * 256;
        bf16x8 v00 = ld_bf16x8(vb);
        bf16x8 v01 = ld_bf16x8(vb + 16);
        bf16x8 v10 = ld_bf16x8(vb + 32 * TSEQ);
        bf16x8 v11 = ld_bf16x8(vb + 32 * TSEQ + 16);

        // S' = Q x K^T   (m = j32 of jc, n = i; 2 itiles)
        f32x16 s0, s1;
#pragma unroll
        for (int r = 0; r < 16; ++r) { s0[r] = 0.f; s1[r] = 0.f; }
#pragma unroll
        for (int ks = 0; ks < 4; ++ks) {
            s0 = mfma32(qc[ks], kf0[ks], s0);
            s1 = mfma32(qc[ks], kf1[ks], s1);
        }

        // prefetch next-step Q frags into the other named buffer (consumed next STEP)
        if (jt + 1 < 16) {
            const unsigned short* qb = qp + (jt + 1) * 16384;
#pragma unroll
            for (int ks = 0; ks < 4; ++ks) qn[ks] = ld_bf16x8(qb + ks * 16);
        }

        // exp2 + pack to bf16 pairs + denominator
        unsigned int pk0[8], pk1[8];
#pragma unroll
        for (int m = 0; m < 8; ++m) {
            float a0 = fast_exp2(s0[2 * m]), a1 = fast_exp2(s0[2 * m + 1]);
            float b0 = fast_exp2(s1[2 * m]), b1 = fast_exp2(s1[2 * m + 1]);
            lac0 += a0 + a1;
            lac1 += b0 + b1;
            bf16x2 ta; ta[0] = (__bf16)a0; ta[1] = (__bf16)a1;
            bf16x2 tb; tb[0] = (__bf16)b0; tb[1] = (__bf16)b1;
            pk0[m] = __builtin_bit_cast(unsigned int, ta);
            pk1[m] = __builtin_bit_cast(unsigned int, tb);
        }

        // PV: O[h][i] += V^T x P ; B-frag of P built by cross-half shfl regroup
#pragma unroll
        for (int k2 = 0; k2 < 2; ++k2) {
            bf16x8 pb0, pb1;
            {
                unsigned int A0 = pk0[k2 * 4 + 0], A1 = pk0[k2 * 4 + 1];
                unsigned int B0 = pk0[k2 * 4 + 2], B1 = pk0[k2 * 4 + 3];
                unsigned int t0 = l5 ? A0 : B0, t1 = l5 ? A1 : B1;
                unsigned int r0 = (unsigned int)__shfl_xor((int)t0, 32, 64);
                unsigned int r1 = (unsigned int)__shfl_xor((int)t1, 32, 64);
                uint4v u;
                u[0] = l5 ? r0 : A0; u[1] = l5 ? r1 : A1;
                u[2] = l5 ? B0 : r0; u[3] = l5 ? B1 : r1;
                pb0 = __builtin_bit_cast(bf16x8, u);
            }
            {
                unsigned int A0 = pk1[k2 * 4 + 0], A1 = pk1[k2 * 4 + 1];
                unsigned int B0 = pk1[k2 * 4 + 2], B1 = pk1[k2 * 4 + 3];
                unsigned int t0 = l5 ? A0 : B0, t1 = l5 ? A1 : B1;
                unsigned int r0 = (unsigned int)__shfl_xor((int)t0, 32, 64);
                unsigned int r1 = (unsigned int)__shfl_xor((int)t1, 32, 64);
                uint4v u;
                u[0] = l5 ? r0 : A0; u[1] = l5 ? r1 : A1;
                u[2] = l5 ? B0 : r0; u[3] = l5 ? B1 : r1;
                pb1 = __builtin_bit_cast(bf16x8, u);
            }
            bf16x8 vf0 = k2 ? v01 : v00;
            bf16x8 vf1 = k2 ? v11 : v10;
            o00 = mfma32(vf0, pb0, o00);
            o01 = mfma32(vf0, pb1, o01);
            o10 = mfma32(vf1, pb0, o10);
            o11 = mfma32(vf1, pb1, o11);
        }
    };

#pragma unroll 1
    for (int jt = 0; jt < 16; jt += 2) {
        STEP(qA, qB, jt);
        STEP(qB, qA, jt + 1);
    }

    // ---- epilogue: combine jc partials, divide by L, write out ----
    lac0 += __shfl_xor(lac0, 32, 64);
    lac1 += __shfl_xor(lac1, 32, 64);
    if (l5 == 0) {
        ldsl[jc * 64 + l31] = lac0;
        ldsl[jc * 64 + 32 + l31] = lac1;
    }
    __syncthreads();
    if (tid < 64) {
        float L = 0.f;
#pragma unroll
        for (int j = 0; j < 8; ++j) L += ldsl[j * 64 + tid];
        Lrec[tid] = 1.0f / L;
    }
    __syncthreads();

#pragma unroll
    for (int ph = 0; ph < 4; ++ph) {
        const int ht = ph >> 1, it = ph & 1;
        const f32x16 ov = (ph == 0) ? o00 : (ph == 1) ? o01 : (ph == 2) ? o10 : o11;
#pragma unroll
        for (int r = 0; r < 16; ++r) {
            int hr = (r & 3) + 8 * (r >> 2) + 4 * l5;
            OCp[(jc * 32 + hr) * 34 + l31] = ov[r];
        }
        __syncthreads();
#pragma unroll
        for (int rep = 0; rep < 2; ++rep) {
            int idx = rep * 512 + tid;
            int i = idx >> 5, hr = idx & 31;
            float s = 0.f;
#pragma unroll
            for (int j = 0; j < 8; ++j) s += OCp[(j * 32 + hr) * 34 + i];
            out[(size_t)(ibase + it * 32 + i) * HD + ht * 32 + hr] = s * Lrec[it * 32 + i];
        }
        if (ph < 3) __syncthreads();
    }
}

extern "C" void kernel_launch(void* const* d_in, const int* in_sizes, int n_in,
                              void* d_out, int out_size, void* d_ws, size_t ws_size,
                              hipStream_t stream) {
    (void)in_sizes; (void)n_in; (void)out_size; (void)ws_size;
    const float* x  = (const float*)d_in[0];
    const float* Wk = (const float*)d_in[1];
    const float* bk = (const float*)d_in[2];
    const float* Wq = (const float*)d_in[3];
    const float* bq = (const float*)d_in[4];
    const float* Wv = (const float*)d_in[5];
    const float* bv = (const float*)d_in[6];

    char* ws = (char*)d_ws;
    unsigned short* WT  = (unsigned short*)(ws);               // 192 KiB
    unsigned short* Kw  = (unsigned short*)(ws + 196608);      // 2 MiB
    unsigned short* Qw  = (unsigned short*)(ws + 2293760);     // 2 MiB
    unsigned short* VTw = (unsigned short*)(ws + 4390912);     // 2 MiB
    float* outp = (float*)d_out;

    hipLaunchKernelGGL(prep_wt, dim3(384), dim3(256), 0, stream, Wk, Wq, Wv, WT);
    hipLaunchKernelGGL(proj, dim3(512), dim3(512), 0, stream,
                       x, WT, bk, bq, bv, Kw, Qw, VTw);
    hipLaunchKernelGGL(attn, dim3(256), dim3(512), 0, stream, Kw, Qw, VTw, outp);
}